// Round 5
// baseline (1510.187 us; speedup 1.0000x reference)
//
#include <hip/hip_runtime.h>
#include <hip/hip_bf16.h>
#include <math.h>

typedef unsigned short u16;
typedef __bf16 bf16x8_t __attribute__((ext_vector_type(8)));
typedef float  f32x4_t  __attribute__((ext_vector_type(4)));
typedef float  f32x8_t  __attribute__((ext_vector_type(8)));
typedef u16    u16x4_t  __attribute__((ext_vector_type(4)));
typedef u16    u16x8_t  __attribute__((ext_vector_type(8)));

// ---------- helpers ----------
__device__ __forceinline__ u16 f2b(float f) {
  unsigned u = __builtin_bit_cast(unsigned, f);
  u += 0x7fffu + ((u >> 16) & 1u);      // RNE; inputs are finite
  return (u16)(u >> 16);
}
__device__ __forceinline__ float b2f(u16 h) {
  unsigned u = ((unsigned)h) << 16;
  return __builtin_bit_cast(float, u);
}
__device__ __forceinline__ float sigm_(float x) { return 1.0f / (1.0f + __expf(-x)); }
__device__ __forceinline__ float tanh_(float x) { return 1.0f - 2.0f / (__expf(2.0f * x) + 1.0f); }

__device__ __forceinline__ void gload16(const void* g, void* l) {
  __builtin_amdgcn_global_load_lds(
      (__attribute__((address_space(1))) void*)(g),
      (__attribute__((address_space(3))) void*)(l), 16, 0, 0);
}

// ==========================================================================
// Packed panel format: tiles of 256 rows x 32 k, 16 KB each, laid out as
//   [k-plane p=0..3][row 0..255][8 u16]   (plane = k sub-slice of 8)
// Panel = [row_block][k_tile][tile(8192 u16)], k-tile stride = KT per panel.
// Staging a half-tile = one contiguous 8KB wave-load set (512 thr x 16B),
// LDS image identical to packed tile -> conflict-free ds_read_b128 frags.
// ==========================================================================

// ---------- pack fp32 activations [B,C] -> packed bf16 panel (col offset c0) ----------
__global__ void cvt_act_kernel(const float* __restrict__ src, u16* __restrict__ dst,
                               int C, int KT, int c0) {
  int mb = blockIdx.x, ktl = blockIdx.y, t = threadIdx.x;
  int ktg = (c0 >> 5) + ktl;
  const float* s = src + (long)(mb * 256 + t) * C + ktl * 32;
  u16* d = dst + ((long)(mb * KT + ktg)) * 8192 + t * 8;
#pragma unroll
  for (int p = 0; p < 4; ++p) {
    f32x8_t v = *(const f32x8_t*)(s + p * 8);
    u16x8_t o;
#pragma unroll
    for (int r = 0; r < 8; ++r) o[r] = f2b(v[r]);
    *(u16x8_t*)(d + p * 2048) = o;
  }
}

// ---------- pack fp32 weight [K,N] (transposed) -> packed bf16 panel ----------
__global__ void cvt_wt_kernel(const float* __restrict__ src, u16* __restrict__ dst,
                              int N, int KT, int n0, int k0) {
  int bx = blockIdx.x, by = blockIdx.y, t = threadIdx.x;
  int n = bx * 256 + t;
  int nb_g = (n0 >> 8) + bx;
  int ktg = (k0 >> 5) + by;
  float tmp[32];
#pragma unroll
  for (int kk = 0; kk < 32; ++kk)
    tmp[kk] = src[(long)(by * 32 + kk) * N + n];
  u16* d = dst + ((long)(nb_g * KT + ktg)) * 8192 + t * 8;
#pragma unroll
  for (int p = 0; p < 4; ++p) {
    u16x8_t o;
#pragma unroll
    for (int r = 0; r < 8; ++r) o[r] = f2b(tmp[p * 8 + r]);
    *(u16x8_t*)(d + p * 2048) = o;
  }
}

// ==========================================================================
// 256x256 bf16 GEMM, m201-style 4-phase/K64 schedule, 8 waves (2M x 4N).
// LDS: 2 buffers x [A-T0|A-T1|B-T0|B-T1] x 16KB = 128 KiB.
// Per iter (K=64 = packed tiles T0,T1), 4 phases:
//   ph0: read B-T0 frags + A-T0 rows mh0 | stage A-T0' | bar | lgkm0 | 16 MFMA | bar
//   ph1: read A-T0 rows mh1              | stage B-T0' | bar | lgkm0 | 16 MFMA | vmcnt(4) bar
//   ph2: read B-T1 frags + A-T1 rows mh0 | stage A-T1' | bar | lgkm0 | 16 MFMA | bar
//   ph3: read A-T1 rows mh1              | stage B-T1' | bar | lgkm0 | 16 MFMA | vmcnt(4) bar
// vmcnt(4) checkpoints certify exactly the 2 tiles consumed next (stage order
// == consumption order); never drains to 0 in steady state (T4).
// Operands SWAPPED in MFMA so lane's 4 acc regs = 4 consecutive output cols.
// ==========================================================================
template <int MODE>
__global__ __launch_bounds__(512, 2) void gemm256_kernel(
    const u16* __restrict__ A, const u16* __restrict__ Bt, u16* __restrict__ Cout) {
  constexpr int KTF  = (MODE == 0) ? 160 : 128;  // panel k-tile stride (K32 units)
  constexpr int NCOL = (MODE == 0) ? 8192 : 2048;
  constexpr int NBN  = NCOL / 256;

  __shared__ u16 lds[2 * 4 * 8192];  // 128 KiB

  // XCD-bijective swizzle (grid % 8 == 0 in both modes)
  int bid = blockIdx.x;
  int cpx = gridDim.x >> 3;
  bid = (bid & 7) * cpx + (bid >> 3);

  int mb = bid / NBN, nb = bid % NBN;
  int m0 = mb * 256, n0 = nb * 256;

  int kt0, NT;  // kt0 in K32 tile units, NT = number of K64 iters
  if (MODE == 0) { kt0 = 0; NT = (nb < 16) ? 80 : ((nb < 28) ? 48 : 32); }
  else           { kt0 = (nb < 4) ? 0 : 64; NT = 32; }

  const int tid  = threadIdx.x;
  const int lane = tid & 63;
  const int wid  = tid >> 6;       // 0..7
  const int wr   = wid >> 2;       // 0..1  (wave row: 128 output rows)
  const int wc   = wid & 3;        // 0..3  (wave col: 64 output cols)

  // per-thread staging base (each thread copies 16B of every half-tile)
  const u16* pA = A  + ((long)(mb * KTF + kt0)) * 8192 + tid * 8;
  const u16* pB = Bt + ((long)(nb * KTF + kt0)) * 8192 + tid * 8;
  const int dstg = tid * 8;

  // STG(buf, op, j, h): stage half h of tile j (iter it) of operand op
  // op slots in LDS buffer: 0 = A-T0, 1 = A-T1, 2 = B-T0, 3 = B-T1
#define STG_A(buf, it, j, h) \
    gload16(pA + ((long)(2 * (it) + (j))) * 8192 + (h) * 4096, \
            &lds[(buf) * 32768 + (j) * 8192 + (h) * 4096 + dstg])
#define STG_B(buf, it, j, h) \
    gload16(pB + ((long)(2 * (it) + (j))) * 8192 + (h) * 4096, \
            &lds[(buf) * 32768 + (2 + (j)) * 8192 + (h) * 4096 + dstg])

  // fragment read offsets within a tile (u16): plane(lane>>4)*2048 + row*8
  const int aoff = (lane >> 4) * 2048 + (wr * 128 + (lane & 15)) * 8;  // + mh*512 + m*128
  const int boff = (lane >> 4) * 2048 + (wc * 64  + (lane & 15)) * 8;  // + n*128

  f32x4_t acc[8][4];
#pragma unroll
  for (int m = 0; m < 8; ++m)
#pragma unroll
    for (int n = 0; n < 4; ++n) acc[m][n] = (f32x4_t){0.f, 0.f, 0.f, 0.f};

  // ---- prologue: stage buf0 in consumption order (A0,B0,A1,B1) ----
  STG_A(0, 0, 0, 0); STG_A(0, 0, 0, 1);
  STG_B(0, 0, 0, 0); STG_B(0, 0, 0, 1);
  STG_A(0, 0, 1, 0); STG_A(0, 0, 1, 1);
  STG_B(0, 0, 1, 0); STG_B(0, 0, 1, 1);
  asm volatile("s_waitcnt vmcnt(4)" ::: "memory");   // A-T0,B-T0 resident
  __builtin_amdgcn_s_barrier();

  for (int t = 0; t < NT; ++t) {
    const int buf = t & 1, nxt = buf ^ 1;
    const u16* sb = &lds[buf * 32768];
    const bool pre = (t + 1 < NT);

    bf16x8_t bv[4], av[4];

    // ---------------- phase 0: B-T0 + A-T0 mh0 ----------------
#pragma unroll
    for (int n = 0; n < 4; ++n) bv[n] = *(const bf16x8_t*)&sb[2 * 8192 + boff + n * 128];
#pragma unroll
    for (int m = 0; m < 4; ++m) av[m] = *(const bf16x8_t*)&sb[aoff + m * 128];
    if (pre) { STG_A(nxt, t + 1, 0, 0); STG_A(nxt, t + 1, 0, 1); }
    __builtin_amdgcn_s_barrier();
    asm volatile("s_waitcnt lgkmcnt(0)" ::: "memory");
    __builtin_amdgcn_sched_barrier(0);
    __builtin_amdgcn_s_setprio(1);
#pragma unroll
    for (int m = 0; m < 4; ++m)
#pragma unroll
      for (int n = 0; n < 4; ++n)
        acc[m][n] = __builtin_amdgcn_mfma_f32_16x16x32_bf16(bv[n], av[m], acc[m][n], 0, 0, 0);
    __builtin_amdgcn_s_setprio(0);
    __builtin_amdgcn_s_barrier();

    // ---------------- phase 1: A-T0 mh1 ----------------
#pragma unroll
    for (int m = 0; m < 4; ++m) av[m] = *(const bf16x8_t*)&sb[aoff + 512 + m * 128];
    if (pre) { STG_B(nxt, t + 1, 0, 0); STG_B(nxt, t + 1, 0, 1); }
    __builtin_amdgcn_s_barrier();
    asm volatile("s_waitcnt lgkmcnt(0)" ::: "memory");
    __builtin_amdgcn_sched_barrier(0);
    __builtin_amdgcn_s_setprio(1);
#pragma unroll
    for (int m = 0; m < 4; ++m)
#pragma unroll
      for (int n = 0; n < 4; ++n)
        acc[m + 4][n] = __builtin_amdgcn_mfma_f32_16x16x32_bf16(bv[n], av[m], acc[m + 4][n], 0, 0, 0);
    __builtin_amdgcn_s_setprio(0);
    if (pre) asm volatile("s_waitcnt vmcnt(4)" ::: "memory");  // cur T1 resident
    else     asm volatile("s_waitcnt vmcnt(0)" ::: "memory");
    __builtin_amdgcn_s_barrier();

    // ---------------- phase 2: B-T1 + A-T1 mh0 ----------------
#pragma unroll
    for (int n = 0; n < 4; ++n) bv[n] = *(const bf16x8_t*)&sb[3 * 8192 + boff + n * 128];
#pragma unroll
    for (int m = 0; m < 4; ++m) av[m] = *(const bf16x8_t*)&sb[8192 + aoff + m * 128];
    if (pre) { STG_A(nxt, t + 1, 1, 0); STG_A(nxt, t + 1, 1, 1); }
    __builtin_amdgcn_s_barrier();
    asm volatile("s_waitcnt lgkmcnt(0)" ::: "memory");
    __builtin_amdgcn_sched_barrier(0);
    __builtin_amdgcn_s_setprio(1);
#pragma unroll
    for (int m = 0; m < 4; ++m)
#pragma unroll
      for (int n = 0; n < 4; ++n)
        acc[m][n] = __builtin_amdgcn_mfma_f32_16x16x32_bf16(bv[n], av[m], acc[m][n], 0, 0, 0);
    __builtin_amdgcn_s_setprio(0);
    __builtin_amdgcn_s_barrier();

    // ---------------- phase 3: A-T1 mh1 ----------------
#pragma unroll
    for (int m = 0; m < 4; ++m) av[m] = *(const bf16x8_t*)&sb[8192 + aoff + 512 + m * 128];
    if (pre) { STG_B(nxt, t + 1, 1, 0); STG_B(nxt, t + 1, 1, 1); }
    __builtin_amdgcn_s_barrier();
    asm volatile("s_waitcnt lgkmcnt(0)" ::: "memory");
    __builtin_amdgcn_sched_barrier(0);
    __builtin_amdgcn_s_setprio(1);
#pragma unroll
    for (int m = 0; m < 4; ++m)
#pragma unroll
      for (int n = 0; n < 4; ++n)
        acc[m + 4][n] = __builtin_amdgcn_mfma_f32_16x16x32_bf16(bv[n], av[m], acc[m + 4][n], 0, 0, 0);
    __builtin_amdgcn_s_setprio(0);
    if (pre) asm volatile("s_waitcnt vmcnt(4)" ::: "memory");  // next T0 resident
    else     asm volatile("s_waitcnt vmcnt(0)" ::: "memory");
    __builtin_amdgcn_s_barrier();
  }
#undef STG_A
#undef STG_B

  // epilogue (swapped operands): out row = lane&15, out cols = (lane>>4)*4 + r
  const int rowm = lane & 15;
  const int col4 = (lane >> 4) * 4;
#pragma unroll
  for (int m = 0; m < 8; ++m) {
    long rg = (long)(m0 + wr * 128 + m * 16 + rowm) * NCOL;
#pragma unroll
    for (int n = 0; n < 4; ++n) {
      int cg = n0 + wc * 64 + n * 16 + col4;
      u16x4_t o;
#pragma unroll
      for (int r = 0; r < 4; ++r) o[r] = f2b(acc[m][n][r]);
      *(u16x4_t*)&Cout[rg + cg] = o;
    }
  }
}

// ---------- pass2: gates -> c_new (fp32), A2 packed = [bf16(c_new) | bf16(tanh(c_new))] ----------
__global__ void pass2_kernel(const u16* __restrict__ G1, const float* __restrict__ c_t,
                             const float* __restrict__ bias_i, const float* __restrict__ bias_f,
                             const float* __restrict__ bias_c,
                             float* __restrict__ c_new_out, u16* __restrict__ A2p) {
  int mb = blockIdx.x, jg = blockIdx.y, t = threadIdx.x;
  int b = mb * 256 + t;
  int j0 = jg * 32;
  const u16* row = G1 + (long)b * 8192 + j0;
  const float* cp_p = c_t + (long)b * 2048 + j0;
  float* co_p = c_new_out + (long)b * 2048 + j0;
  u16* dc = A2p + ((long)(mb * 128 + jg)) * 8192 + t * 8;
  u16* dr = dc + (long)64 * 8192;

#pragma unroll
  for (int q = 0; q < 4; ++q) {
    u16x8_t ip = *(const u16x8_t*)(row + q * 8);
    u16x8_t fp = *(const u16x8_t*)(row + 2048 + q * 8);
    u16x8_t gp = *(const u16x8_t*)(row + 4096 + q * 8);
    f32x8_t cp = *(const f32x8_t*)(cp_p + q * 8);
    f32x8_t bi = *(const f32x8_t*)(bias_i + j0 + q * 8);
    f32x8_t bf = *(const f32x8_t*)(bias_f + j0 + q * 8);
    f32x8_t bc = *(const f32x8_t*)(bias_c + j0 + q * 8);
    f32x8_t cn;
    u16x8_t cb, rb;
#pragma unroll
    for (int r = 0; r < 8; ++r) {
      float ig = sigm_(b2f(ip[r]) + bi[r]);
      float fg = sigm_(b2f(fp[r]) + bf[r]);
      float g  = tanh_(b2f(gp[r]) + bc[r]);
      float c  = fg * cp[r] + ig * g;
      cn[r] = c;
      cb[r] = f2b(c);
      rb[r] = f2b(tanh_(c));
    }
    *(f32x8_t*)(co_p + q * 8) = cn;
    *(u16x8_t*)(dc + q * 2048) = cb;
    *(u16x8_t*)(dr + q * 2048) = rb;
  }
}

// ---------- pass3: h_new = sigmoid(og_pre + c@Woc + bias_o) * (m_t + xr) ----------
__global__ void pass3_kernel(const u16* __restrict__ G1, const u16* __restrict__ G2,
                             const float* __restrict__ bias_o, float* __restrict__ h_out) {
  long i = (long)blockIdx.x * blockDim.x + threadIdx.x;
  long e = i * 8;
  int b = (int)(e >> 10);
  int j = (int)(e & 1023);
  const u16* row1 = G1 + (long)b * 8192;
  const u16* row2 = G2 + (long)b * 2048;
  u16x8_t ogp = *(const u16x8_t*)(row1 + 6144 + j);
  u16x8_t xrp = *(const u16x8_t*)(row1 + 7168 + j);
  u16x8_t ocg = *(const u16x8_t*)(row2 + j);
  u16x8_t mt  = *(const u16x8_t*)(row2 + 1024 + j);
  f32x8_t bo  = *(const f32x8_t*)(bias_o + j);
  f32x8_t h;
#pragma unroll
  for (int r = 0; r < 8; ++r) {
    float og = sigm_(b2f(ogp[r]) + b2f(ocg[r]) + bo[r]);
    h[r] = og * (b2f(mt[r]) + b2f(xrp[r]));
  }
  *(f32x8_t*)(h_out + (long)b * 1024 + j) = h;
}

// ---------- launch ----------
extern "C" void kernel_launch(void* const* d_in, const int* in_sizes, int n_in,
                              void* d_out, int out_size, void* d_ws, size_t ws_size,
                              hipStream_t stream) {
  const float* x_t      = (const float*)d_in[0];
  const float* h_t      = (const float*)d_in[1];
  const float* c_t      = (const float*)d_in[2];
  const float* w_if_x   = (const float*)d_in[3];
  const float* w_if_h   = (const float*)d_in[4];
  const float* w_if_c   = (const float*)d_in[5];
  const float* bias_i   = (const float*)d_in[6];
  const float* bias_f   = (const float*)d_in[7];
  const float* w_c_x    = (const float*)d_in[8];
  const float* w_c_h    = (const float*)d_in[9];
  const float* bias_c   = (const float*)d_in[10];
  const float* w_o_x    = (const float*)d_in[11];
  const float* w_o_h    = (const float*)d_in[12];
  const float* w_o_c    = (const float*)d_in[13];
  const float* bias_o   = (const float*)d_in[14];
  const float* w_r_proj = (const float*)d_in[15];
  const float* w_r_x    = (const float*)d_in[16];

  char* ws = (char*)d_ws;
  u16* A1p  = (u16*)(ws);
  u16* W1tp = (u16*)(ws + 167772160L);
  u16* G1   = (u16*)(ws + 251658240L);
  u16* W2tp = (u16*)(ws + 520093696L);
  u16* A2p  = (u16*)(ws);               // aliases A1p (dead after GEMM1)
  u16* G2   = (u16*)(ws + 167772160L);  // aliases W1tp (dead after GEMM1)

  float* h_out = (float*)d_out;
  float* c_out = h_out + 16384L * 1024L;

  // --- stage 0: pack activations (A1 panel k-map: x 0..63, h 64..95, c 96..159) ---
  cvt_act_kernel<<<dim3(64, 64), 256, 0, stream>>>(x_t, A1p, 2048, 160, 0);
  cvt_act_kernel<<<dim3(64, 32), 256, 0, stream>>>(h_t, A1p, 1024, 160, 2048);
  cvt_act_kernel<<<dim3(64, 64), 256, 0, stream>>>(c_t, A1p, 2048, 160, 3072);

  // --- pack weights (transposed) ---
  cvt_wt_kernel<<<dim3(16, 64), 256, 0, stream>>>(w_if_x,   W1tp, 4096, 160, 0,    0);
  cvt_wt_kernel<<<dim3(16, 32), 256, 0, stream>>>(w_if_h,   W1tp, 4096, 160, 0,    2048);
  cvt_wt_kernel<<<dim3(16, 64), 256, 0, stream>>>(w_if_c,   W1tp, 4096, 160, 0,    3072);
  cvt_wt_kernel<<<dim3(8,  64), 256, 0, stream>>>(w_c_x,    W1tp, 2048, 160, 4096, 0);
  cvt_wt_kernel<<<dim3(8,  32), 256, 0, stream>>>(w_c_h,    W1tp, 2048, 160, 4096, 2048);
  cvt_wt_kernel<<<dim3(4,  64), 256, 0, stream>>>(w_o_x,    W1tp, 1024, 160, 6144, 0);
  cvt_wt_kernel<<<dim3(4,  32), 256, 0, stream>>>(w_o_h,    W1tp, 1024, 160, 6144, 2048);
  cvt_wt_kernel<<<dim3(4,  64), 256, 0, stream>>>(w_r_x,    W1tp, 1024, 160, 7168, 0);
  cvt_wt_kernel<<<dim3(4,  64), 256, 0, stream>>>(w_o_c,    W2tp, 1024, 128, 0,    0);
  cvt_wt_kernel<<<dim3(4,  64), 256, 0, stream>>>(w_r_proj, W2tp, 1024, 128, 1024, 2048);

  // --- stage 1: big fused GEMM -> all pre-activations ---
  gemm256_kernel<0><<<2048, 512, 0, stream>>>(A1p, W1tp, G1);

  // --- stage 2: elementwise gates -> c_new + packed A2 ---
  pass2_kernel<<<dim3(64, 64), 256, 0, stream>>>(G1, c_t, bias_i, bias_f, bias_c, c_out, A2p);

  // --- stage 3: [c_new|r_t] GEMM -> og peephole + m_t ---
  gemm256_kernel<1><<<512, 512, 0, stream>>>(A2p, W2tp, G2);

  // --- stage 4: h_new ---
  pass3_kernel<<<8192, 256, 0, stream>>>(G1, G2, bias_o, h_out);
}